// Round 1
// baseline (654.486 us; speedup 1.0000x reference)
//
#include <hip/hip_runtime.h>

// Problem constants (from reference)
constexpr int E = 64, I = 512, O = 512, T = 131072, CAP = 3072;

// GEMM tiling
constexpr int BM = 128, BN = 128, BK = 32;
constexpr int MT = CAP / BM;   // 24 m-tiles per expert (capacity-bounded)
constexpr int NT = O / BN;     // 4 n-tiles
constexpr int NK = I / BK;     // 16 k-iters
constexpr int LDA = BK + 8;    // padded LDS stride in shorts: 80 B keeps 16B align, 2-way bank alias only

typedef __bf16 bf16x8 __attribute__((ext_vector_type(8)));
typedef float floatx4 __attribute__((ext_vector_type(4)));

// Pack two fp32 -> two bf16 (round-to-nearest via +0x8000, then take high halves with v_perm)
__device__ inline unsigned pack_bf16(float a, float b) {
  unsigned ua = __float_as_uint(a) + 0x8000u;
  unsigned ub = __float_as_uint(b) + 0x8000u;
  // result = { ub.b3, ub.b2, ua.b3, ua.b2 } = (bf16(b) << 16) | bf16(a)
  return __builtin_amdgcn_perm(ub, ua, 0x07060302);
}

// ---------------------------------------------------------------------------
// Kernel 1: bucket tokens by expert. counts are padded to one 64B line each.
// Tokens overflowing CAP (never happens for this input) get zero output rows.
// ---------------------------------------------------------------------------
__global__ void scatter_k(const int* __restrict__ ids, int* __restrict__ counts,
                          int* __restrict__ bucket, float* __restrict__ out) {
  int t = blockIdx.x * blockDim.x + threadIdx.x;
  if (t >= T) return;
  int e = ids[t];
  int pos = atomicAdd(&counts[e * 16], 1);
  if (pos < CAP) {
    bucket[e * CAP + pos] = t;
  } else {
    float4 z = make_float4(0.f, 0.f, 0.f, 0.f);
    float* op = out + (size_t)t * O;
    for (int i = 0; i < O; i += 4) *(float4*)(op + i) = z;
  }
}

// ---------------------------------------------------------------------------
// Kernel 2: grouped GEMM. block = (expert, m-tile, n-tile). 256 threads.
// A = gathered x rows (K-major), B = weight[e] rows (K-major) -> C = A * B^T.
// fp32 -> bf16 conversion fused into LDS staging; mfma_f32_16x16x32_bf16.
// ---------------------------------------------------------------------------
__global__ __launch_bounds__(256) void moe_gemm(
    const float* __restrict__ x, const float* __restrict__ w,
    const float* __restrict__ bias, const int* __restrict__ counts,
    const int* __restrict__ bucket, float* __restrict__ out) {
  const int bid = blockIdx.x;
  const int e  = bid / (MT * NT);
  const int mt = (bid / NT) % MT;
  const int nt = bid % NT;

  int cnt = counts[e * 16];
  if (cnt > CAP) cnt = CAP;
  if (mt * BM >= cnt) return;   // empty m-tile for this expert

  __shared__ __align__(16) short As[BM * LDA];
  __shared__ __align__(16) short Bs[BN * LDA];
  __shared__ int toks[BM];

  const int t = threadIdx.x;
  if (t < BM) {
    int g = mt * BM + t;
    toks[t] = (g < cnt) ? bucket[e * CAP + g] : -1;
  }
  __syncthreads();

  // Staging assignment: 8 threads per row (float4 each), 32 rows per pass, 4 passes.
  const int c4 = t & 7;        // which float4 within BK=32
  const int rb = t >> 3;       // row 0..31 (then +32*j)

  const float* aptr[4];
  const float* bptr[4];
#pragma unroll
  for (int j = 0; j < 4; ++j) {
    int r = rb + 32 * j;
    int tk = toks[r]; if (tk < 0) tk = 0;   // safe dummy row for padding
    aptr[j] = x + (size_t)tk * I + (c4 << 2);
    bptr[j] = w + (size_t)e * (O * I) + (size_t)(nt * BN + r) * I + (c4 << 2);
  }

  const int lane = t & 63;
  const int wv = t >> 6;            // wave 0..3
  const int wm = wv >> 1, wn = wv & 1;   // 2x2 wave grid, each wave 64x64
  const int lrow = lane & 15;
  const int quad = lane >> 4;

  floatx4 acc[4][4] = {};

  int aoff[4], boff[4];
#pragma unroll
  for (int mmi = 0; mmi < 4; ++mmi)
    aoff[mmi] = (wm * 64 + mmi * 16 + lrow) * LDA + quad * 8;
#pragma unroll
  for (int nni = 0; nni < 4; ++nni)
    boff[nni] = (wn * 64 + nni * 16 + lrow) * LDA + quad * 8;
  const int wroff0 = rb * LDA + (c4 << 2);

  // Register-prefetched staging: load k-slab kk+1 while MFMAs of kk issue.
  float4 av[2][4], bv[2][4];
#pragma unroll
  for (int j = 0; j < 4; ++j) {
    av[0][j] = *(const float4*)aptr[j];
    bv[0][j] = *(const float4*)bptr[j];
  }

#pragma unroll
  for (int kk = 0; kk < NK; ++kk) {
    const int cur = kk & 1, nxt = cur ^ 1;
    __syncthreads();   // previous iter's LDS reads done
#pragma unroll
    for (int j = 0; j < 4; ++j) {
      float4 f = av[cur][j];
      *(uint2*)&As[wroff0 + j * 32 * LDA] =
          make_uint2(pack_bf16(f.x, f.y), pack_bf16(f.z, f.w));
    }
#pragma unroll
    for (int j = 0; j < 4; ++j) {
      float4 f = bv[cur][j];
      *(uint2*)&Bs[wroff0 + j * 32 * LDA] =
          make_uint2(pack_bf16(f.x, f.y), pack_bf16(f.z, f.w));
    }
    if (kk + 1 < NK) {
#pragma unroll
      for (int j = 0; j < 4; ++j) {
        aptr[j] += BK; bptr[j] += BK;
        av[nxt][j] = *(const float4*)aptr[j];
        bv[nxt][j] = *(const float4*)bptr[j];
      }
    }
    __syncthreads();   // LDS writes visible

    bf16x8 af[4], bfr[4];
#pragma unroll
    for (int mmi = 0; mmi < 4; ++mmi) af[mmi] = *(const bf16x8*)&As[aoff[mmi]];
#pragma unroll
    for (int nni = 0; nni < 4; ++nni) bfr[nni] = *(const bf16x8*)&Bs[boff[nni]];
#pragma unroll
    for (int mmi = 0; mmi < 4; ++mmi)
#pragma unroll
      for (int nni = 0; nni < 4; ++nni)
        acc[mmi][nni] = __builtin_amdgcn_mfma_f32_16x16x32_bf16(
            af[mmi], bfr[nni], acc[mmi][nni], 0, 0, 0);
  }

  // Epilogue: add bias, scatter rows back to out[token].
  float bb[4];
#pragma unroll
  for (int nni = 0; nni < 4; ++nni)
    bb[nni] = bias[e * O + nt * BN + wn * 64 + nni * 16 + lrow];

  const int colbase = nt * BN + wn * 64 + lrow;
#pragma unroll
  for (int mmi = 0; mmi < 4; ++mmi) {
    const int rl = wm * 64 + mmi * 16 + quad * 4;
#pragma unroll
    for (int i = 0; i < 4; ++i) {
      const int tk = toks[rl + i];
      if (tk >= 0) {
        float* op = out + (size_t)tk * O + colbase;
#pragma unroll
        for (int nni = 0; nni < 4; ++nni)
          op[nni * 16] = acc[mmi][nni][i] + bb[nni];
      }
    }
  }
}

extern "C" void kernel_launch(void* const* d_in, const int* in_sizes, int n_in,
                              void* d_out, int out_size, void* d_ws, size_t ws_size,
                              hipStream_t stream) {
  const float* x    = (const float*)d_in[0];
  const float* w    = (const float*)d_in[1];
  const float* bias = (const float*)d_in[2];
  const int*   ids  = (const int*)d_in[3];
  float* out = (float*)d_out;

  // Workspace layout: [0, 4KB) padded counts (64 x 16 ints), then bucket (E*CAP ints, 768KB)
  int* counts = (int*)d_ws;
  int* bucket = counts + 16 * E;

  hipMemsetAsync(counts, 0, 16 * E * sizeof(int), stream);
  scatter_k<<<dim3(T / 256), dim3(256), 0, stream>>>(ids, counts, bucket, out);
  moe_gemm<<<dim3(E * MT * NT), dim3(256), 0, stream>>>(x, w, bias, counts, bucket, out);
}